// Round 9
// baseline (343.782 us; speedup 1.0000x reference)
//
#include <hip/hip_runtime.h>

#define NEG_SLOPE 0.2f
#define SHARD_CAP 1024   // per-(bin,shard) pair capacity; 8 shards/bin, mean ~510

typedef short s16x8 __attribute__((ext_vector_type(8)));
typedef float f32x4 __attribute__((ext_vector_type(4)));
typedef float f32x2 __attribute__((ext_vector_type(2)));
typedef unsigned int u32x4 __attribute__((ext_vector_type(4)));

typedef __attribute__((address_space(3))) unsigned int lds_u32;
typedef __attribute__((address_space(1))) const unsigned int glb_u32;

__device__ __forceinline__ unsigned short f2bf(float f) {
    unsigned int u = __float_as_uint(f);
    unsigned int r = (u + 0x7fffu + ((u >> 16) & 1u)) >> 16;
    return (unsigned short)r;
}
__device__ __forceinline__ float bf2f(unsigned int us) {
    return __uint_as_float(us << 16);
}

// volatile asm load: emitted AT THE WRITE SITE (cannot be sunk past the softmax
// by the scheduler). Consumer side must wait: s_waitcnt vmcnt(0) + sched_barrier.
__device__ __forceinline__ u32x4 gload16(const char* p) {
    u32x4 r;
    asm volatile("global_load_dwordx4 %0, %1, off" : "=v"(r) : "v"(p));
    return r;
}

// ---------------- pass 1: coarse-bin partition + wl precompute + W split-bf16 ----------------

__global__ __launch_bounds__(256) void binpart_k(
        const int* __restrict__ src, const int* __restrict__ dst, int E,
        int* __restrict__ bin_cur, int* __restrict__ ovf_n,
        int2* __restrict__ pairs,
        int* __restrict__ ovf_dst, int* __restrict__ ovf_src,
        const float* __restrict__ W1, const float* __restrict__ al1,
        const float* __restrict__ ar1,
        const float* __restrict__ W2, const float* __restrict__ al2,
        const float* __restrict__ ar2,
        float* __restrict__ wl1, float* __restrict__ wl2,
        unsigned short* __restrict__ Bt1h, unsigned short* __restrict__ Bt1l,
        unsigned short* __restrict__ Bt2h, unsigned short* __restrict__ Bt2l) {
    const int b = blockIdx.x;
    if (b == 0) {   // block-uniform branch
        int k = threadIdx.x; // 256
        #pragma unroll
        for (int h = 0; h < 4; h++) {
            float sl = 0.f, sr = 0.f;
            #pragma unroll 8
            for (int d = 0; d < 64; d++) {
                float wv = W1[k * 256 + h * 64 + d];
                sl = fmaf(wv, al1[h * 64 + d], sl);
                sr = fmaf(wv, ar1[h * 64 + d], sr);
            }
            wl1[k * 8 + h] = sl;
            wl1[k * 8 + 4 + h] = sr;
        }
        float sl = 0.f, sr = 0.f;
        #pragma unroll 8
        for (int d = 0; d < 128; d++) {
            float wv = W2[k * 128 + d];
            sl = fmaf(wv, al2[d], sl);
            sr = fmaf(wv, ar2[d], sr);
        }
        wl2[k * 2 + 0] = sl;
        wl2[k * 2 + 1] = sr;
        return;
    }
    if (b <= 4) {   // W1 [K=256][256] -> Bt1[col][256] hi/lo
        int c = (b - 1) * 64 + (threadIdx.x >> 2);
        int kq = threadIdx.x & 3;
        #pragma unroll 8
        for (int kk = 0; kk < 64; kk++) {
            int k = kq + kk * 4;
            float w = W1[k * 256 + c];
            unsigned short h = f2bf(w);
            unsigned short l = f2bf(w - bf2f(h));
            Bt1h[c * 256 + k] = h;
            Bt1l[c * 256 + k] = l;
        }
        return;
    }
    if (b <= 6) {   // W2 [K=256][128] -> Bt2[col][256] hi/lo
        int c = (b - 5) * 64 + (threadIdx.x >> 2);
        int kq = threadIdx.x & 3;
        #pragma unroll 8
        for (int kk = 0; kk < 64; kk++) {
            int k = kq + kk * 4;
            float w = W2[k * 128 + c];
            unsigned short h = f2bf(w);
            unsigned short l = f2bf(w - bf2f(h));
            Bt2h[c * 256 + k] = h;
            Bt2l[c * 256 + k] = l;
        }
        return;
    }
    // ---- partition 2048 edges ----
    __shared__ int l_cnt[256];
    __shared__ int l_base[256];
    const int tid = threadIdx.x;
    const int pb = b - 7;
    const int shard = pb & 7;
    const int base_e = pb * 2048 + tid * 8;
    int s[8], d[8], bn[8], rk[8];
    bool v[8];
    if (base_e + 7 < E) {
        int4 a0 = *(const int4*)(src + base_e);
        int4 a1 = *(const int4*)(src + base_e + 4);
        int4 c0 = *(const int4*)(dst + base_e);
        int4 c1 = *(const int4*)(dst + base_e + 4);
        s[0]=a0.x; s[1]=a0.y; s[2]=a0.z; s[3]=a0.w;
        s[4]=a1.x; s[5]=a1.y; s[6]=a1.z; s[7]=a1.w;
        d[0]=c0.x; d[1]=c0.y; d[2]=c0.z; d[3]=c0.w;
        d[4]=c1.x; d[5]=c1.y; d[6]=c1.z; d[7]=c1.w;
        #pragma unroll
        for (int i = 0; i < 8; i++) v[i] = true;
    } else {
        #pragma unroll
        for (int i = 0; i < 8; i++) {
            int e = base_e + i;
            v[i] = e < E;
            s[i] = v[i] ? src[e] : 0;
            d[i] = v[i] ? dst[e] : 0;
        }
    }
    l_cnt[tid] = 0;
    __syncthreads();
    #pragma unroll
    for (int i = 0; i < 8; i++) {
        bn[i] = d[i] >> 8;
        if (v[i]) rk[i] = atomicAdd(&l_cnt[bn[i]], 1);
    }
    __syncthreads();
    {
        int c = l_cnt[tid];
        if (c > 0) l_base[tid] = atomicAdd(&bin_cur[(tid * 8 + shard) * 16], c);
    }
    __syncthreads();
    #pragma unroll
    for (int i = 0; i < 8; i++) {
        if (v[i]) {
            int pos = l_base[bn[i]] + rk[i];
            if (pos < SHARD_CAP) {
                int2 p; p.x = s[i]; p.y = d[i];
                pairs[(((size_t)bn[i] * 8 + shard) << 10) + pos] = p;
            } else {   // astronomically rare; correctness fallback
                int j = atomicAdd(ovf_n, 1);
                ovf_dst[j] = d[i]; ovf_src[j] = s[i];
            }
        }
    }
}

// ---------------- pass 2 (fused): binfill blocks [0,nbin) + prep blocks [nbin,..) ----------------

__global__ __launch_bounds__(256) void prepfill_k(
        const int* __restrict__ bin_cur, const int2* __restrict__ pairs,
        int* __restrict__ cnt, int* __restrict__ bucket,
        int* __restrict__ ovf_n, int* __restrict__ ovf_dst, int* __restrict__ ovf_src,
        const float* __restrict__ feat, const float* __restrict__ wl1,
        unsigned short* __restrict__ Ah, unsigned short* __restrict__ Al,
        float* __restrict__ el1, float* __restrict__ er1, int Nn, int nbin) {
    if ((int)blockIdx.x < nbin) {
        __shared__ int l_cnt[256];
        const int b = blockIdx.x;
        const int tid = threadIdx.x;
        l_cnt[tid] = 0;
        __syncthreads();
        #pragma unroll
        for (int sh = 0; sh < 8; sh++) {
            const int ec = min(bin_cur[(b * 8 + sh) * 16], SHARD_CAP);
            const int2* pp = pairs + (((size_t)b * 8 + sh) << 10);
            for (int i = tid; i < ec; i += 256) {
                int2 p = pp[i];
                int pos = atomicAdd(&l_cnt[p.y & 255], 1);
                if (pos < 64) bucket[((size_t)p.y << 6) + pos] = p.x;
                else {   // node deg > 64: rare fallback
                    int j = atomicAdd(ovf_n, 1);
                    ovf_dst[j] = p.y; ovf_src[j] = p.x;
                }
            }
        }
        __syncthreads();
        int node = b * 256 + tid;
        if (node < Nn) cnt[node] = l_cnt[tid];
        return;
    }
    const int lane = threadIdx.x & 63, wid = threadIdx.x >> 6;
    const int n = ((int)blockIdx.x - nbin) * 4 + wid;
    if (n >= Nn) return;
    float4 f = ((const float4*)(feat + (size_t)n * 256))[lane];
    unsigned short h0 = f2bf(f.x), h1 = f2bf(f.y), h2 = f2bf(f.z), h3 = f2bf(f.w);
    unsigned short l0 = f2bf(f.x - bf2f(h0)), l1 = f2bf(f.y - bf2f(h1));
    unsigned short l2 = f2bf(f.z - bf2f(h2)), l3 = f2bf(f.w - bf2f(h3));
    uint2 hv, lv;
    hv.x = (unsigned)h0 | ((unsigned)h1 << 16);
    hv.y = (unsigned)h2 | ((unsigned)h3 << 16);
    lv.x = (unsigned)l0 | ((unsigned)l1 << 16);
    lv.y = (unsigned)l2 | ((unsigned)l3 << 16);
    ((uint2*)(Ah + (size_t)n * 256))[lane] = hv;
    ((uint2*)(Al + (size_t)n * 256))[lane] = lv;

    float ff[4] = {f.x, f.y, f.z, f.w};
    float pa[4] = {0.f, 0.f, 0.f, 0.f}, pb[4] = {0.f, 0.f, 0.f, 0.f};
    const float* wp = wl1 + lane * 32;
    #pragma unroll
    for (int j = 0; j < 4; j++) {
        float4 wa = *(const float4*)(wp + j * 8);
        float4 wb = *(const float4*)(wp + j * 8 + 4);
        pa[0] = fmaf(ff[j], wa.x, pa[0]); pa[1] = fmaf(ff[j], wa.y, pa[1]);
        pa[2] = fmaf(ff[j], wa.z, pa[2]); pa[3] = fmaf(ff[j], wa.w, pa[3]);
        pb[0] = fmaf(ff[j], wb.x, pb[0]); pb[1] = fmaf(ff[j], wb.y, pb[1]);
        pb[2] = fmaf(ff[j], wb.z, pb[2]); pb[3] = fmaf(ff[j], wb.w, pb[3]);
    }
    #pragma unroll
    for (int h = 0; h < 4; h++) {
        #pragma unroll
        for (int o = 32; o > 0; o >>= 1) {
            pa[h] += __shfl_xor(pa[h], o);
            pb[h] += __shfl_xor(pb[h], o);
        }
    }
    if (lane == 0) {
        ((float4*)el1)[n] = float4{pa[0], pa[1], pa[2], pa[3]};
        ((float4*)er1)[n] = float4{pb[0], pb[1], pb[2], pb[3]};
    }
}

// ---------------- pure split-bf16 MFMA GEMM, global_load_lds staging ----------------

__global__ __launch_bounds__(256) void gemm_k(const unsigned short* __restrict__ Ah,
                                              const unsigned short* __restrict__ Al,
                                              const unsigned short* __restrict__ Bh,
                                              const unsigned short* __restrict__ Bl,
                                              unsigned short* __restrict__ Cb,
                                              int M, int Nc) {
    __shared__ __align__(16) unsigned short SB[12288];   // 24 KB

    const int tid = threadIdx.x;
    const int lane = tid & 63, wid = tid >> 6;
    const int row0 = blockIdx.y * 128;
    const int col0 = blockIdx.x * 64;
    const int wm = (wid & 1) * 64;
    const int wn = (wid >> 1) * 32;
    const int quad = lane >> 4, mrow = lane & 15;

    const unsigned short* gb[6];
    unsigned ldsoff[6];
    {
        const int lr = lane >> 2;
        const int kc = (lane & 3) * 8;
        #pragma unroll
        for (int j = 0; j < 6; j++) {
            int c = wid * 6 + j;
            const unsigned short* base;
            int row;
            if (c < 8)       { base = Ah; row = min(row0 + c * 16 + lr, M - 1); }
            else if (c < 16) { base = Al; row = min(row0 + (c - 8) * 16 + lr, M - 1); }
            else if (c < 20) { base = Bh; row = col0 + (c - 16) * 16 + lr; }
            else             { base = Bl; row = col0 + (c - 20) * 16 + lr; }
            gb[j] = base + (size_t)row * 256 + kc;
            ldsoff[j] = (unsigned)c * 512;   // ushort units; 1KB per chunk
        }
    }

    f32x4 acc[4][2];
    #pragma unroll
    for (int i = 0; i < 4; i++)
        #pragma unroll
        for (int j = 0; j < 2; j++) acc[i][j] = f32x4{0.f, 0.f, 0.f, 0.f};

    for (int kt = 0; kt < 8; kt++) {
        __syncthreads();                       // prev iter's frag reads complete
        #pragma unroll
        for (int j = 0; j < 6; j++) {
            __builtin_amdgcn_global_load_lds((glb_u32*)(gb[j] + kt * 32),
                                             (lds_u32*)&SB[ldsoff[j]], 16, 0, 0);
        }
        __syncthreads();                       // compiler drains vmcnt before barrier

        s16x8 ah[4], al4[4], bh[2], bl[2];
        #pragma unroll
        for (int i = 0; i < 4; i++) {
            int r = wm + 16 * i + mrow;
            ah[i]  = *(const s16x8*)&SB[r * 32 + quad * 8];
            al4[i] = *(const s16x8*)&SB[4096 + r * 32 + quad * 8];
        }
        #pragma unroll
        for (int j = 0; j < 2; j++) {
            int r = wn + 16 * j + mrow;
            bh[j] = *(const s16x8*)&SB[8192 + r * 32 + quad * 8];
            bl[j] = *(const s16x8*)&SB[10240 + r * 32 + quad * 8];
        }
        #pragma unroll
        for (int i = 0; i < 4; i++)
            #pragma unroll
            for (int j = 0; j < 2; j++) {
                acc[i][j] = __builtin_amdgcn_mfma_f32_16x16x32_bf16(ah[i],  bh[j], acc[i][j], 0, 0, 0);
                acc[i][j] = __builtin_amdgcn_mfma_f32_16x16x32_bf16(ah[i],  bl[j], acc[i][j], 0, 0, 0);
                acc[i][j] = __builtin_amdgcn_mfma_f32_16x16x32_bf16(al4[i], bh[j], acc[i][j], 0, 0, 0);
            }
    }

    #pragma unroll
    for (int i = 0; i < 4; i++) {
        #pragma unroll
        for (int j = 0; j < 2; j++) {
            int col = col0 + wn + 16 * j + mrow;
            int rbase = row0 + wm + 16 * i + quad * 4;
            #pragma unroll
            for (int r = 0; r < 4; r++) {
                int row = rbase + r;
                if (row < M) Cb[(size_t)row * Nc + col] = f2bf(acc[i][j][r]);
            }
        }
    }
}

// ---------------- fused edge-softmax + wide-row gather-aggregate ----------------
// one WAVE per node. 8-deep register window via VOLATILE asm loads (cannot be
// sunk past the softmax); one s_waitcnt vmcnt(0) + sched_barrier before consume.

__device__ __forceinline__ void fma8(f32x2* acc, float wgt, u32x4 u) {
    f32x2 w2; w2.x = wgt; w2.y = wgt;
    f32x2 p;
    p.x = __uint_as_float(u.x << 16); p.y = __uint_as_float(u.x & 0xffff0000u);
    acc[0] = p * w2 + acc[0];
    p.x = __uint_as_float(u.y << 16); p.y = __uint_as_float(u.y & 0xffff0000u);
    acc[1] = p * w2 + acc[1];
    p.x = __uint_as_float(u.z << 16); p.y = __uint_as_float(u.z & 0xffff0000u);
    acc[2] = p * w2 + acc[2];
    p.x = __uint_as_float(u.w << 16); p.y = __uint_as_float(u.w & 0xffff0000u);
    acc[3] = p * w2 + acc[3];
}

template <int H, int D, bool RELU, bool FUSE2>
__global__ __launch_bounds__(256) void fagg_k(const unsigned short* __restrict__ ft,
                                              const float* __restrict__ el,
                                              const float* __restrict__ er,
                                              const int* __restrict__ cnt,
                                              const int* __restrict__ bucket,
                                              const int* __restrict__ ovf_n,
                                              const int* __restrict__ ovf_dst,
                                              const int* __restrict__ ovf_src,
                                              const float* __restrict__ bias,
                                              float* __restrict__ out, int n_nodes,
                                              unsigned short* __restrict__ oh,
                                              unsigned short* __restrict__ ol,
                                              const float* __restrict__ wl2,
                                              float* __restrict__ el2,
                                              float* __restrict__ er2) {
    constexpr int HD = H * D;
    constexpr int LPE = HD / 8;    // lanes per edge-row (16B/lane): 32 (L1), 16 (L2)
    constexpr int EPI = 64 / LPE;  // edges per wave-load: 2 (L1), 4 (L2)
    constexpr int SH = (HD == 256) ? 9 : 8;   // log2(row bytes)
    const int lane = threadIdx.x & 63;
    const int w = threadIdx.x >> 6;
    const int n = blockIdx.x * 4 + w;
    __shared__ int   s_src[4][64];
    __shared__ float s_a[4][64 * H];
    if (n >= n_nodes) return;
    const int deg = cnt[n];
    const int novf = *ovf_n;
    const int lane_sub = lane & (LPE - 1);
    const int q = lane / LPE;
    const int c0 = lane_sub * 8;
    const int h_of = c0 / D;
    const unsigned lsub16 = (unsigned)(lane_sub * 16);
    const char* fb = (const char*)ft;
    const char* eb = (const char*)el;

    float ern[H];
    #pragma unroll
    for (int h = 0; h < H; h++) ern[h] = er[n * H + h];

    f32x2 acc[4];
    #pragma unroll
    for (int t = 0; t < 4; t++) acc[t] = f32x2{0.f, 0.f};

    const int* s_src_w = s_src[w];
    const float* s_a_w = s_a[w];

#define GADDR(i) (fb + (((unsigned)s_src_w[(i) * EPI + q] << SH) + lsub16))
#define WT(i)    (s_a_w[((i) * EPI + q) * H + h_of])

    if (deg <= 64 && novf == 0) {
        // ---- fast path ----
        const bool act = lane < deg;
        int sv = act ? bucket[(n << 6) + lane] : 0;
        s_src[w][lane] = sv;
        float evr[H];
        if constexpr (H == 4) {
            float4 e4 = *(const float4*)(eb + ((unsigned)sv << 4));
            evr[0] = e4.x; evr[1] = e4.y; evr[2] = e4.z; evr[3] = e4.w;
        } else {
            evr[0] = *(const float*)(eb + ((unsigned)sv << 2));
        }
        const int nl = (deg + EPI - 1) / EPI;   // rounds with real edges
        // 8-deep window, issued HERE (volatile asm, un-sinkable); pad-safe slots <= 63
        u32x4 v0 = gload16(GADDR(0)), v1 = gload16(GADDR(1));
        u32x4 v2 = gload16(GADDR(2)), v3 = gload16(GADDR(3));
        u32x4 v4 = gload16(GADDR(4)), v5 = gload16(GADDR(5));
        u32x4 v6 = gload16(GADDR(6)), v7 = gload16(GADDR(7));
        // max-free softmax overlaps the loads' flight time
        float ex[H], sm[H];
        #pragma unroll
        for (int h = 0; h < H; h++) {
            float t = evr[h] + ern[h];
            t = t > 0.f ? t : NEG_SLOPE * t;
            ex[h] = act ? __expf(t) : 0.f;
            sm[h] = ex[h];
        }
        #pragma unroll
        for (int h = 0; h < H; h++)
            for (int o = 32; o > 0; o >>= 1) sm[h] += __shfl_xor(sm[h], o);
        #pragma unroll
        for (int h = 0; h < H; h++)
            s_a[w][lane * H + h] = ex[h] * (sm[h] > 0.f ? 1.f / sm[h] : 0.f);
        // drain the window; fence consumer hoisting (rule #18)
        asm volatile("s_waitcnt vmcnt(0)" ::: "memory");
        __builtin_amdgcn_sched_barrier(0);
        fma8(acc, WT(0), v0); fma8(acc, WT(1), v1);
        fma8(acc, WT(2), v2); fma8(acc, WT(3), v3);
        fma8(acc, WT(4), v4); fma8(acc, WT(5), v5);
        fma8(acc, WT(6), v6); fma8(acc, WT(7), v7);
        // guarded tail, chunk-of-4 (plain loads; slot <= 63 pad-safe)
        constexpr int MAXNL = 64 / EPI;   // 32 (L1), 16 (L2)
        #pragma unroll
        for (int i0 = 8; i0 < MAXNL; i0 += 4) {
            if (i0 >= nl) break;
            u32x4 a  = *(const u32x4*)GADDR(i0);
            u32x4 b2 = *(const u32x4*)GADDR(i0 + 1);
            u32x4 c2 = *(const u32x4*)GADDR(i0 + 2);
            u32x4 d2 = *(const u32x4*)GADDR(i0 + 3);
            fma8(acc, WT(i0), a);      fma8(acc, WT(i0 + 1), b2);
            fma8(acc, WT(i0 + 2), c2); fma8(acc, WT(i0 + 3), d2);
        }
    } else {
        // ---- rare slow path: masked bucket entries + overflow list ----
        const int bval = deg < 64 ? deg : 64;
        const bool act = lane < bval;
        int sv0 = act ? bucket[(n << 6) + lane] : 0;
        s_src[w][lane] = sv0;
        float sm[H];
        #pragma unroll
        for (int h = 0; h < H; h++) sm[h] = 0.f;
        {
            float evr[H];
            if constexpr (H == 4) {
                float4 e4 = ((const float4*)el)[sv0];
                evr[0] = e4.x; evr[1] = e4.y; evr[2] = e4.z; evr[3] = e4.w;
            } else evr[0] = el[sv0];
            #pragma unroll
            for (int h = 0; h < H; h++) {
                float t = evr[h] + ern[h];
                t = t > 0.f ? t : NEG_SLOPE * t;
                if (act) sm[h] += __expf(t);
            }
        }
        for (int i = lane; i < novf; i += 64) {
            if (ovf_dst[i] == n) {
                int sv = ovf_src[i];
                float evr[H];
                if constexpr (H == 4) {
                    float4 e4 = ((const float4*)el)[sv];
                    evr[0] = e4.x; evr[1] = e4.y; evr[2] = e4.z; evr[3] = e4.w;
                } else evr[0] = el[sv];
                #pragma unroll
                for (int h = 0; h < H; h++) {
                    float t = evr[h] + ern[h];
                    t = t > 0.f ? t : NEG_SLOPE * t;
                    sm[h] += __expf(t);
                }
            }
        }
        #pragma unroll
        for (int h = 0; h < H; h++)
            for (int o = 32; o > 0; o >>= 1) sm[h] += __shfl_xor(sm[h], o);
        float inv[H];
        #pragma unroll
        for (int h = 0; h < H; h++) inv[h] = (sm[h] > 0.f) ? (1.f / sm[h]) : 0.f;
        {   // weights for the bucket entries (0 for pads)
            float evr[H];
            if constexpr (H == 4) {
                float4 e4 = ((const float4*)el)[sv0];
                evr[0] = e4.x; evr[1] = e4.y; evr[2] = e4.z; evr[3] = e4.w;
            } else evr[0] = el[sv0];
            #pragma unroll
            for (int h = 0; h < H; h++) {
                float t = evr[h] + ern[h];
                t = t > 0.f ? t : NEG_SLOPE * t;
                s_a[w][lane * H + h] = act ? __expf(t) * inv[h] : 0.f;
            }
        }
        for (int e = q; e < 64; e += EPI) {
            unsigned bo = ((unsigned)s_src_w[e] << SH) + lsub16;
            u32x4 v = *(const u32x4*)(fb + bo);
            fma8(acc, s_a_w[e * H + h_of], v);
        }
        // overflow edges, one at a time (static select chains; no dynamic reg indexing)
        for (int i = 0; i < novf; i++) {
            if (ovf_dst[i] != n) continue;
            int sv = ovf_src[i];
            float elh, ernh, invh;
            if constexpr (H == 4) {
                float4 e4 = ((const float4*)el)[sv];
                elh  = (h_of & 2) ? ((h_of & 1) ? e4.w : e4.z)
                                  : ((h_of & 1) ? e4.y : e4.x);
                ernh = (h_of & 2) ? ((h_of & 1) ? ern[3] : ern[2])
                                  : ((h_of & 1) ? ern[1] : ern[0]);
                invh = (h_of & 2) ? ((h_of & 1) ? inv[3] : inv[2])
                                  : ((h_of & 1) ? inv[1] : inv[0]);
            } else {
                elh = el[sv]; ernh = ern[0]; invh = inv[0];
            }
            float t = elh + ernh;
            t = t > 0.f ? t : NEG_SLOPE * t;
            float wt = __expf(t) * invh;
            u32x4 v = *(const u32x4*)(fb + (((unsigned)sv << SH) + lsub16));
            if (q == 0) fma8(acc, wt, v);
        }
    }
#undef GADDR
#undef WT

    float accs[8];
    #pragma unroll
    for (int t = 0; t < 8; t++) accs[t] = acc[t >> 1][t & 1];

    // cross-lane combine: edge sub-groups fold into lanes [0, LPE)
    #pragma unroll
    for (int t = 0; t < 8; t++) {
        #pragma unroll
        for (int s = LPE; s < 64; s <<= 1) accs[t] += __shfl_xor(accs[t], s);
    }
    if (lane < LPE) {
        float4 b0 = ((const float4*)bias)[lane * 2];
        float4 b1 = ((const float4*)bias)[lane * 2 + 1];
        float v[8] = {accs[0] + b0.x, accs[1] + b0.y, accs[2] + b0.z, accs[3] + b0.w,
                      accs[4] + b1.x, accs[5] + b1.y, accs[6] + b1.z, accs[7] + b1.w};
        if (RELU) {
            #pragma unroll
            for (int t = 0; t < 8; t++) v[t] = fmaxf(v[t], 0.f);
        }
        if constexpr (FUSE2) {
            unsigned short hh[8], ll[8];
            #pragma unroll
            for (int t = 0; t < 8; t++) {
                hh[t] = f2bf(v[t]);
                ll[t] = f2bf(v[t] - bf2f(hh[t]));
            }
            uint4 hv, lv;
            hv.x = (unsigned)hh[0] | ((unsigned)hh[1] << 16);
            hv.y = (unsigned)hh[2] | ((unsigned)hh[3] << 16);
            hv.z = (unsigned)hh[4] | ((unsigned)hh[5] << 16);
            hv.w = (unsigned)hh[6] | ((unsigned)hh[7] << 16);
            lv.x = (unsigned)ll[0] | ((unsigned)ll[1] << 16);
            lv.y = (unsigned)ll[2] | ((unsigned)ll[3] << 16);
            lv.z = (unsigned)ll[4] | ((unsigned)ll[5] << 16);
            lv.w = (unsigned)ll[6] | ((unsigned)ll[7] << 16);
            ((uint4*)(oh + (size_t)n * HD))[lane] = hv;
            ((uint4*)(ol + (size_t)n * HD))[lane] = lv;
            float pa = 0.f, pb = 0.f;
            #pragma unroll
            for (int t = 0; t < 8; t++) {
                float2 wv = ((const float2*)wl2)[lane * 8 + t];
                pa = fmaf(v[t], wv.x, pa);
                pb = fmaf(v[t], wv.y, pb);
            }
            #pragma unroll
            for (int o = 16; o > 0; o >>= 1) {
                pa += __shfl_xor(pa, o);
                pb += __shfl_xor(pb, o);
            }
            if (lane == 0) { el2[n] = pa; er2[n] = pb; }
        } else {
            float4 o0{v[0], v[1], v[2], v[3]};
            float4 o1{v[4], v[5], v[6], v[7]};
            float4* op = (float4*)out + (size_t)n * (HD / 4) + lane * 2;
            op[0] = o0;
            op[1] = o1;
        }
    }
}

// ---------------- launch ----------------

extern "C" void kernel_launch(void* const* d_in, const int* in_sizes, int n_in,
                              void* d_out, int out_size, void* d_ws, size_t ws_size,
                              hipStream_t stream) {
    const float* feat    = (const float*)d_in[0];
    const int*   src     = (const int*)d_in[1];
    const int*   dst     = (const int*)d_in[2];
    const float* W1      = (const float*)d_in[3];
    const float* attn_l1 = (const float*)d_in[4];
    const float* attn_r1 = (const float*)d_in[5];
    const float* bias1   = (const float*)d_in[6];
    const float* W2      = (const float*)d_in[7];
    const float* attn_l2 = (const float*)d_in[8];
    const float* attn_r2 = (const float*)d_in[9];
    const float* bias2   = (const float*)d_in[10];
    float* out = (float*)d_out;

    const int N = in_sizes[0] / 256;   // 50000
    const int E = in_sizes[1];         // 800000
    const int nbin = (N + 255) >> 8;   // 196
    const int nbP = (E + 2047) / 2048; // 391

    char* ws = (char*)d_ws;
    size_t o = 0;
    auto alloc = [&](size_t bytes) -> void* {
        void* p = ws + o;
        o = (o + bytes + 255) & ~(size_t)255;
        return p;
    };
    int* bin_cur = (int*)alloc(((size_t)nbin * 8 * 16 + 64) * 4);
    int* ovf_n   = bin_cur + (size_t)nbin * 8 * 16;
    int* cnt     = (int*)alloc((size_t)N * 4);
    int* bucket  = (int*)alloc((size_t)N * 64 * 4);
    int* ovf_dst = (int*)alloc((size_t)E * 4);
    int* ovf_src = (int*)alloc((size_t)E * 4);
    float* wl1 = (float*)alloc(256 * 8 * 4);
    float* wl2 = (float*)alloc(256 * 2 * 4);
    float* el1 = (float*)alloc((size_t)N * 4 * 4);
    float* er1 = (float*)alloc((size_t)N * 4 * 4);
    float* el2 = (float*)alloc((size_t)N * 4);
    float* er2 = (float*)alloc((size_t)N * 4);
    unsigned short* ft1b = (unsigned short*)alloc((size_t)N * 256 * 2);
    unsigned short* Ah   = (unsigned short*)alloc((size_t)N * 256 * 2);
    unsigned short* Al   = (unsigned short*)alloc((size_t)N * 256 * 2);
    unsigned short* Bt1h = (unsigned short*)alloc((size_t)256 * 256 * 2);
    unsigned short* Bt1l = (unsigned short*)alloc((size_t)256 * 256 * 2);
    unsigned short* Bt2h = (unsigned short*)alloc((size_t)128 * 256 * 2);
    unsigned short* Bt2l = (unsigned short*)alloc((size_t)128 * 256 * 2);
    unsigned short* ft2b = ft1b;   // ft1b dead after layer-1 aggregation
    unsigned short* h1h  = Ah;     // feat split-bf16 dead after layer-1 GEMM
    unsigned short* h1l  = Al;
    int2* pairs = (int2*)ft1b;     // pairs dead before gemm1 writes ft1b (12.8MB <= 25.6MB)

    hipMemsetAsync(bin_cur, 0, ((size_t)nbin * 8 * 16 + 64) * 4, stream);
    binpart_k<<<7 + nbP, 256, 0, stream>>>(src, dst, E, bin_cur, ovf_n, pairs,
                                           ovf_dst, ovf_src,
                                           W1, attn_l1, attn_r1, W2, attn_l2, attn_r2,
                                           wl1, wl2, Bt1h, Bt1l, Bt2h, Bt2l);
    prepfill_k<<<nbin + (N + 3) / 4, 256, 0, stream>>>(bin_cur, pairs, cnt, bucket,
                                                       ovf_n, ovf_dst, ovf_src,
                                                       feat, wl1, Ah, Al, el1, er1, N, nbin);

    // layer 1: H=4, D=64
    gemm_k<<<dim3(4, (N + 127) / 128), 256, 0, stream>>>(Ah, Al, Bt1h, Bt1l, ft1b, N, 256);
    fagg_k<4, 64, true, true><<<(N + 3) / 4, 256, 0, stream>>>(ft1b, el1, er1, cnt, bucket,
                                                               ovf_n, ovf_dst, ovf_src,
                                                               bias1, nullptr, N,
                                                               h1h, h1l, wl2, el2, er2);

    // layer 2: H=1, D=128
    gemm_k<<<dim3(2, (N + 127) / 128), 256, 0, stream>>>(h1h, h1l, Bt2h, Bt2l, ft2b, N, 128);
    fagg_k<1, 128, false, false><<<(N + 3) / 4, 256, 0, stream>>>(ft2b, el2, er2, cnt, bucket,
                                                                  ovf_n, ovf_dst, ovf_src,
                                                                  bias2, out, N,
                                                                  nullptr, nullptr, nullptr,
                                                                  nullptr, nullptr);
}